// Round 5
// baseline (195.673 us; speedup 1.0000x reference)
//
#include <hip/hip_runtime.h>

#define B_DIM 8
#define M_MICS 8
#define F_DIM 257
#define T_DIM 2000
#define NPROB (B_DIM * F_DIM)   // 2056

// Per-problem MVDR weights, written by K1, read by K2 (deterministic, graph-safe).
__device__ float g_w[NPROB * 16];

// Pair q-index enumeration (m<n):
// m=0: q=0..6 ; m=1: q=7..12 ; m=2: q=13..17 ; m=3: q=18..21
// m=4: q=22..24 ; m=5: q=25,26 ; m=6: q=27
// Wave-split of the 130 accumulators:
//  wave0: [0]=msum_s [1]=msum_n [2..9]=ss_diag [10..17]=nn_diag
//         [18+4q+t] for q=0..3 (t: 0=ss_re 1=ss_im 2=nn_re 3=nn_im)   (34)
//  wave1: q=4..11  -> [4*(q-4)+t]
//  wave2: q=12..19 -> [4*(q-12)+t]
//  wave3: q=20..27 -> [4*(q-20)+t]

#define PAIR_ACC(mq, nq, k)                                             \
    {                                                                   \
        const float pr = yr[mq][u] * yr[nq][u] + yi[mq][u] * yi[nq][u]; \
        const float pi = yi[mq][u] * yr[nq][u] - yr[mq][u] * yi[nq][u]; \
        acc[(k) + 0] += msv[u] * pr;                                    \
        acc[(k) + 1] += msv[u] * pi;                                    \
        acc[(k) + 2] += mnv[u] * pr;                                    \
        acc[(k) + 3] += mnv[u] * pi;                                    \
    }

// ==================== K1: covariance + solve (weights out) ===================
// min-waves history: (256,4) -> 64 VGPR + scratch spill (WRITE 58-116MB, rounds 2/3).
// (256,2) -> no spill but AGPR-padded, 2 waves/SIMD, 69% latency stall (round 4).
// (256,3): cap ~170 regs, est. live ~126 -> 3 waves/SIMD, no spill.
__launch_bounds__(256, 3)
__global__ void cov_solve_kernel(const float* __restrict__ sre, const float* __restrict__ sim,
                                 const float* __restrict__ smask, const float* __restrict__ nmask)
{
    const int f = blockIdx.x, b = blockIdx.y, tid = threadIdx.x;
    const int h = tid >> 6, l = tid & 63;   // wave id, lane

    __shared__ float sG[4][34];

    const size_t mrow = (size_t)F_DIM * T_DIM;
    const size_t base_bf = ((size_t)(b * M_MICS) * F_DIM + f) * T_DIM;
    const size_t mbase   = ((size_t)b * F_DIM + f) * T_DIM;

    float acc[34];
#pragma unroll
    for (int i = 0; i < 34; ++i) acc[i] = 0.f;

    // ----- covariance accumulation: float4 per thread, all 4 waves same data ---
#pragma unroll 1
    for (int it = 0; it < 8; ++it) {
        const int t0 = 4 * l + 256 * it;
        if (t0 < T_DIM) {           // T_DIM % 4 == 0, so t0+3 is in-bounds too
            float yr[8][4], yi[8][4];
#pragma unroll
            for (int m = 0; m < 8; ++m) {
                const float4 vr = *reinterpret_cast<const float4*>(sre + base_bf + (size_t)m * mrow + t0);
                const float4 vi = *reinterpret_cast<const float4*>(sim + base_bf + (size_t)m * mrow + t0);
                yr[m][0] = vr.x; yr[m][1] = vr.y; yr[m][2] = vr.z; yr[m][3] = vr.w;
                yi[m][0] = vi.x; yi[m][1] = vi.y; yi[m][2] = vi.z; yi[m][3] = vi.w;
            }
            const float4 ms4 = *reinterpret_cast<const float4*>(smask + mbase + t0);
            const float4 mn4 = *reinterpret_cast<const float4*>(nmask + mbase + t0);
            const float msv[4] = { ms4.x, ms4.y, ms4.z, ms4.w };
            const float mnv[4] = { mn4.x, mn4.y, mn4.z, mn4.w };

            if (h == 0) {
#pragma unroll
                for (int u = 0; u < 4; ++u) {
                    acc[0] += msv[u];
                    acc[1] += mnv[u];
#pragma unroll
                    for (int m = 0; m < 8; ++m) {
                        const float pd = yr[m][u] * yr[m][u] + yi[m][u] * yi[m][u];
                        acc[2 + m]  += msv[u] * pd;
                        acc[10 + m] += mnv[u] * pd;
                    }
                    PAIR_ACC(0, 1, 18) PAIR_ACC(0, 2, 22) PAIR_ACC(0, 3, 26) PAIR_ACC(0, 4, 30)
                }
            } else if (h == 1) {
#pragma unroll
                for (int u = 0; u < 4; ++u) {
                    PAIR_ACC(0, 5, 0)  PAIR_ACC(0, 6, 4)  PAIR_ACC(0, 7, 8)  PAIR_ACC(1, 2, 12)
                    PAIR_ACC(1, 3, 16) PAIR_ACC(1, 4, 20) PAIR_ACC(1, 5, 24) PAIR_ACC(1, 6, 28)
                }
            } else if (h == 2) {
#pragma unroll
                for (int u = 0; u < 4; ++u) {
                    PAIR_ACC(1, 7, 0)  PAIR_ACC(2, 3, 4)  PAIR_ACC(2, 4, 8)  PAIR_ACC(2, 5, 12)
                    PAIR_ACC(2, 6, 16) PAIR_ACC(2, 7, 20) PAIR_ACC(3, 4, 24) PAIR_ACC(3, 5, 28)
                }
            } else {
#pragma unroll
                for (int u = 0; u < 4; ++u) {
                    PAIR_ACC(3, 6, 0)  PAIR_ACC(3, 7, 4)  PAIR_ACC(4, 5, 8)  PAIR_ACC(4, 6, 12)
                    PAIR_ACC(4, 7, 16) PAIR_ACC(5, 6, 20) PAIR_ACC(5, 7, 24) PAIR_ACC(6, 7, 28)
                }
            }
        }
    }

    // ----- per-wave butterfly reduction, lane 0 -> LDS ------------------------
#pragma unroll
    for (int i = 0; i < 34; ++i) {
        acc[i] += __shfl_xor(acc[i], 1, 64);
        acc[i] += __shfl_xor(acc[i], 2, 64);
        acc[i] += __shfl_xor(acc[i], 4, 64);
        acc[i] += __shfl_xor(acc[i], 8, 64);
        acc[i] += __shfl_xor(acc[i], 16, 64);
        acc[i] += __shfl_xor(acc[i], 32, 64);
    }
    if (l == 0) {
#pragma unroll
        for (int i = 0; i < 34; ++i) sG[h][i] = acc[i];
    }
    __syncthreads();

    // ----- solve: wave 0 only, lane = (r, c) of the 8x8 -----------------------
    if (tid < 64) {
        const int r = tid >> 3, cc = tid & 7;
        const float Ssum = sG[0][0] + 1e-8f;
        const float Nsum = sG[0][1] + 1e-8f;

        float ssr, ssi, ar, ai;
        if (r == cc) {
            ssr = sG[0][2 + r] / Ssum;  ssi = 0.f;
            ar  = sG[0][10 + r] / Nsum + 1e-5f;  ai = 0.f;
        } else {
            const int mm  = (r < cc) ? r : cc;
            const int nn2 = (r < cc) ? cc : r;
            const int q = mm * 8 - mm * (mm + 1) / 2 + nn2 - mm - 1;
            const int g = (q < 4) ? 0 : (1 + ((q - 4) >> 3));
            const int basei = (q < 4) ? (18 + 4 * q) : (4 * ((q - 4) & 7));
            const float sgn = (r < cc) ? 1.f : -1.f;
            ssr = sG[g][basei] / Ssum;
            ssi = sgn * sG[g][basei + 1] / Ssum;
            ar  = sG[g][basei + 2] / Nsum;
            ai  = sgn * sG[g][basei + 3] / Nsum;
        }

        // Gauss-Jordan inverse of Phi_nn (Hermitian PD)
        float br = (r == cc) ? 1.f : 0.f, bi = 0.f;
        for (int k = 0; k < 8; ++k) {
            const float pr = __shfl(ar, k * 9, 64);
            const float pi = __shfl(ai, k * 9, 64);
            const float den = pr * pr + pi * pi;
            const float qr = pr / den, qi = -pi / den;
            const bool isk = (r == k);
            const float ar2 = ar * qr - ai * qi;
            const float ai2 = ar * qi + ai * qr;
            const float br2 = br * qr - bi * qi;
            const float bi2 = br * qi + bi * qr;
            ar = isk ? ar2 : ar; ai = isk ? ai2 : ai;
            br = isk ? br2 : br; bi = isk ? bi2 : bi;
            const float rar = __shfl(ar, k * 8 + cc, 64);
            const float rai = __shfl(ai, k * 8 + cc, 64);
            const float rbr = __shfl(br, k * 8 + cc, 64);
            const float rbi = __shfl(bi, k * 8 + cc, 64);
            const float fr = __shfl(ar, r * 8 + k, 64);
            const float fi = __shfl(ai, r * 8 + k, 64);
            const float uar = ar - (fr * rar - fi * rai);
            const float uai = ai - (fr * rai + fi * rar);
            const float ubr = br - (fr * rbr - fi * rbi);
            const float ubi = bi - (fr * rbi + fi * rbr);
            ar = isk ? ar : uar; ai = isk ? ai : uai;
            br = isk ? br : ubr; bi = isk ? bi : ubi;
        }

        // G = Phi_nn_inv @ Phi_ss
        float gr = 0.f, gi = 0.f;
        for (int k = 0; k < 8; ++k) {
            const float ir = __shfl(br, r * 8 + k, 64);
            const float ii = __shfl(bi, r * 8 + k, 64);
            const float skr = __shfl(ssr, k * 8 + cc, 64);
            const float ski = __shfl(ssi, k * 8 + cc, 64);
            gr += ir * skr - ii * ski;
            gi += ir * ski + ii * skr;
        }

        // power iteration (30 iters)
        float vr = 1.f, vi = 0.f;
        for (int itp = 0; itp < 30; ++itp) {
            float wr2 = gr * vr - gi * vi;
            float wi2 = gr * vi + gi * vr;
            wr2 += __shfl_xor(wr2, 1, 64); wi2 += __shfl_xor(wi2, 1, 64);
            wr2 += __shfl_xor(wr2, 2, 64); wi2 += __shfl_xor(wi2, 2, 64);
            wr2 += __shfl_xor(wr2, 4, 64); wi2 += __shfl_xor(wi2, 4, 64);
            float nrm = wr2 * wr2 + wi2 * wi2;
            nrm += __shfl_xor(nrm, 8, 64);
            nrm += __shfl_xor(nrm, 16, 64);
            nrm += __shfl_xor(nrm, 32, 64);
            const float inv = 1.f / (sqrtf(nrm) + 1e-12f);
            wr2 *= inv; wi2 *= inv;
            vr = __shfl(wr2, cc * 9, 64);
            vi = __shfl(wi2, cc * 9, 64);
        }

        // rtf = v / (v[0] + 1e-8)
        const float v0r = __shfl(vr, 0, 64) + 1e-8f;
        const float v0i = __shfl(vi, 0, 64);
        const float dd = v0r * v0r + v0i * v0i;
        const float rtr = (vr * v0r + vi * v0i) / dd;
        const float rti = (vi * v0r - vr * v0i) / dd;

        // d = Phi_nn_inv @ rtf
        float dr = br * rtr - bi * rti;
        float di = br * rti + bi * rtr;
        dr += __shfl_xor(dr, 1, 64); di += __shfl_xor(di, 1, 64);
        dr += __shfl_xor(dr, 2, 64); di += __shfl_xor(di, 2, 64);
        dr += __shfl_xor(dr, 4, 64); di += __shfl_xor(di, 4, 64);

        float qden = (r == cc) ? (rtr * dr + rti * di) : 0.f;
        qden += __shfl_xor(qden, 1, 64); qden += __shfl_xor(qden, 2, 64);
        qden += __shfl_xor(qden, 4, 64); qden += __shfl_xor(qden, 8, 64);
        qden += __shfl_xor(qden, 16, 64); qden += __shfl_xor(qden, 32, 64);
        qden += 1e-8f;

        if (cc == 0) {
            const int p = b * F_DIM + f;
            g_w[p * 16 + r]     = dr / qden;
            g_w[p * 16 + 8 + r] = di / qden;
        }
    }
}

// ============================ K2: apply (pure streaming, proven) =============
__launch_bounds__(256, 8)
__global__ void apply_kernel(const float* __restrict__ sre, const float* __restrict__ sim,
                             float* __restrict__ out, int out_mode)
{
    const int f = blockIdx.x, b = blockIdx.y, z = blockIdx.z;
    const int tid = threadIdx.x;
    __shared__ float sW[16];
    const int p = b * F_DIM + f;
    if (tid < 16) sW[tid] = g_w[p * 16 + tid];
    __syncthreads();

    const int t0 = z * 512 + 2 * tid;
    if (t0 >= T_DIM) return;

    const size_t mrow = (size_t)F_DIM * T_DIM;
    const size_t base_bf = ((size_t)(b * M_MICS) * F_DIM + f) * T_DIM;
    const size_t mbase   = ((size_t)b * F_DIM + f) * T_DIM;

    float er0 = 0.f, ei0 = 0.f, er1 = 0.f, ei1 = 0.f;
#pragma unroll
    for (int m = 0; m < 8; ++m) {
        const float2 vr2 = *reinterpret_cast<const float2*>(sre + base_bf + (size_t)m * mrow + t0);
        const float2 vi2 = *reinterpret_cast<const float2*>(sim + base_bf + (size_t)m * mrow + t0);
        const float wr = sW[m], wi = sW[8 + m];
        er0 += wr * vr2.x + wi * vi2.x;
        ei0 += wr * vi2.x - wi * vr2.x;
        er1 += wr * vr2.y + wi * vi2.y;
        ei1 += wr * vi2.y - wi * vr2.y;
    }
    if (out_mode == 2) {
        *reinterpret_cast<float4*>(out + 2 * (mbase + t0)) = make_float4(er0, ei0, er1, ei1);
    } else {
        *reinterpret_cast<float2*>(out + mbase + t0) = make_float2(er0, er1);
    }
}

extern "C" void kernel_launch(void* const* d_in, const int* in_sizes, int n_in,
                              void* d_out, int out_size, void* d_ws, size_t ws_size,
                              hipStream_t stream)
{
    const float* sre   = (const float*)d_in[0];
    const float* sim   = (const float*)d_in[1];
    const float* smask = (const float*)d_in[2];
    const float* nmask = (const float*)d_in[3];
    float* out = (float*)d_out;

    const int mode = (out_size >= 2 * B_DIM * F_DIM * T_DIM) ? 2 : 1;

    cov_solve_kernel<<<dim3(F_DIM, B_DIM), 256, 0, stream>>>(sre, sim, smask, nmask);
    apply_kernel<<<dim3(F_DIM, B_DIM, 4), 256, 0, stream>>>(sre, sim, out, mode);
}

// Round 6
// 174.328 us; speedup vs baseline: 1.1224x; 1.1224x over previous
//
#include <hip/hip_runtime.h>

#define B_DIM 8
#define M_MICS 8
#define F_DIM 257
#define T_DIM 2000
#define NPROB (B_DIM * F_DIM)   // 2056

// Per-problem MVDR weights, written by K1, read by K2 (deterministic, graph-safe).
__device__ float g_w[NPROB * 16];

// Pair q enumeration (m<n), q = m*8 - m(m+1)/2 + n - m - 1:
// q0-3:(0,1)(0,2)(0,3)(0,4)  q4-7:(0,5)(0,6)(0,7)(1,2)  q8-11:(1,3)(1,4)(1,5)(1,6)
// q12-15:(1,7)(2,3)(2,4)(2,5) q16-19:(2,6)(2,7)(3,4)(3,5) q20-23:(3,6)(3,7)(4,5)(4,6)
// q24-27:(4,7)(5,6)(5,7)(6,7)
// 8-wave split: wave0 = msums+diags (18 acc, float2 path);
// wave w (1..7) = pairs q in [4w-4, 4w), acc[4*(q&3)+t], t:0=ss_re 1=ss_im 2=nn_re 3=nn_im.
// Solve reads: diag -> sG[0][2+m]/sG[0][10+m]; pair q -> sG[1+(q>>2)][4*(q&3)+t].

#define PAIR_ACC(a, bb, k)                                              \
    {                                                                   \
        const float pr = yr[a][u] * yr[bb][u] + yi[a][u] * yi[bb][u];   \
        const float pi = yi[a][u] * yr[bb][u] - yr[a][u] * yi[bb][u];   \
        acc[(k) + 0] += msv[u] * pr;                                    \
        acc[(k) + 1] += msv[u] * pi;                                    \
        acc[(k) + 2] += mnv[u] * pr;                                    \
        acc[(k) + 3] += mnv[u] * pi;                                    \
    }

#define LOAD4(k, m)                                                                                 \
    {                                                                                               \
        const float4 vr_ = *reinterpret_cast<const float4*>(sre + base_bf + (size_t)(m) * mrow + t0); \
        const float4 vi_ = *reinterpret_cast<const float4*>(sim + base_bf + (size_t)(m) * mrow + t0); \
        yr[k][0] = vr_.x; yr[k][1] = vr_.y; yr[k][2] = vr_.z; yr[k][3] = vr_.w;                     \
        yi[k][0] = vi_.x; yi[k][1] = vi_.y; yi[k][2] = vi_.z; yi[k][3] = vi_.w;                     \
    }

#define MASK4                                                                              \
    const float4 ms4 = *reinterpret_cast<const float4*>(smask + mbase + t0);               \
    const float4 mn4 = *reinterpret_cast<const float4*>(nmask + mbase + t0);               \
    const float msv[4] = { ms4.x, ms4.y, ms4.z, ms4.w };                                   \
    const float mnv[4] = { mn4.x, mn4.y, mn4.z, mn4.w };

#define PAIR_LOOP(BODY_LOADS, BODY_ACCS, KMICS)                         \
    {                                                                   \
        _Pragma("unroll 1")                                             \
        for (int it = 0; it < 8; ++it) {                                \
            const int t0 = 4 * l + 256 * it;                            \
            if (t0 < T_DIM) {                                           \
                float yr[KMICS][4], yi[KMICS][4];                       \
                BODY_LOADS                                              \
                MASK4                                                   \
                _Pragma("unroll")                                       \
                for (int u = 0; u < 4; ++u) { BODY_ACCS }               \
            }                                                           \
        }                                                               \
    }

// ==================== K1: covariance + solve (weights out) ===================
// History: forcing dense acc (34/thread) either AGPR-pads to 256 (2 waves/SIMD,
// r4) or scratch-spills under a cap (r2/3/5). This version: 8 waves/problem,
// <=16-18 acc and <=6 mics live per wave -> max live ~75 regs under a 128 cap.
__launch_bounds__(512, 4)
__global__ void cov_solve_kernel(const float* __restrict__ sre, const float* __restrict__ sim,
                                 const float* __restrict__ smask, const float* __restrict__ nmask)
{
    const int f = blockIdx.x, b = blockIdx.y, tid = threadIdx.x;
    const int h = tid >> 6, l = tid & 63;   // wave id (0..7), lane

    __shared__ float sG[8][20];

    const size_t mrow = (size_t)F_DIM * T_DIM;
    const size_t base_bf = ((size_t)(b * M_MICS) * F_DIM + f) * T_DIM;
    const size_t mbase   = ((size_t)b * F_DIM + f) * T_DIM;

    float acc[18];
#pragma unroll
    for (int i = 0; i < 18; ++i) acc[i] = 0.f;

    if (h == 0) {
        // msums + diagonals, float2 path (8 mics live but half-width)
#pragma unroll 1
        for (int it = 0; it < 16; ++it) {
            const int t0 = 2 * l + 128 * it;
            if (t0 < T_DIM) {
                float yr[8][2], yi[8][2];
#pragma unroll
                for (int m = 0; m < 8; ++m) {
                    const float2 vr_ = *reinterpret_cast<const float2*>(sre + base_bf + (size_t)m * mrow + t0);
                    const float2 vi_ = *reinterpret_cast<const float2*>(sim + base_bf + (size_t)m * mrow + t0);
                    yr[m][0] = vr_.x; yr[m][1] = vr_.y;
                    yi[m][0] = vi_.x; yi[m][1] = vi_.y;
                }
                const float2 ms2 = *reinterpret_cast<const float2*>(smask + mbase + t0);
                const float2 mn2 = *reinterpret_cast<const float2*>(nmask + mbase + t0);
                const float msv[2] = { ms2.x, ms2.y };
                const float mnv[2] = { mn2.x, mn2.y };
#pragma unroll
                for (int u = 0; u < 2; ++u) {
                    acc[0] += msv[u];
                    acc[1] += mnv[u];
#pragma unroll
                    for (int m = 0; m < 8; ++m) {
                        const float pd = yr[m][u] * yr[m][u] + yi[m][u] * yi[m][u];
                        acc[2 + m]  += msv[u] * pd;
                        acc[10 + m] += mnv[u] * pd;
                    }
                }
            }
        }
    } else if (h == 1) {
        // q0-3: (0,1)(0,2)(0,3)(0,4); mics 0,1,2,3,4
        PAIR_LOOP(LOAD4(0,0) LOAD4(1,1) LOAD4(2,2) LOAD4(3,3) LOAD4(4,4),
                  PAIR_ACC(0,1,0) PAIR_ACC(0,2,4) PAIR_ACC(0,3,8) PAIR_ACC(0,4,12), 5)
    } else if (h == 2) {
        // q4-7: (0,5)(0,6)(0,7)(1,2); mics 0,1,2,5,6,7 -> local 0,1,2,3,4,5
        PAIR_LOOP(LOAD4(0,0) LOAD4(1,1) LOAD4(2,2) LOAD4(3,5) LOAD4(4,6) LOAD4(5,7),
                  PAIR_ACC(0,3,0) PAIR_ACC(0,4,4) PAIR_ACC(0,5,8) PAIR_ACC(1,2,12), 6)
    } else if (h == 3) {
        // q8-11: (1,3)(1,4)(1,5)(1,6); mics 1,3,4,5,6 -> local 0,1,2,3,4
        PAIR_LOOP(LOAD4(0,1) LOAD4(1,3) LOAD4(2,4) LOAD4(3,5) LOAD4(4,6),
                  PAIR_ACC(0,1,0) PAIR_ACC(0,2,4) PAIR_ACC(0,3,8) PAIR_ACC(0,4,12), 5)
    } else if (h == 4) {
        // q12-15: (1,7)(2,3)(2,4)(2,5); mics 1,2,3,4,5,7 -> local 0,1,2,3,4,5
        PAIR_LOOP(LOAD4(0,1) LOAD4(1,2) LOAD4(2,3) LOAD4(3,4) LOAD4(4,5) LOAD4(5,7),
                  PAIR_ACC(0,5,0) PAIR_ACC(1,2,4) PAIR_ACC(1,3,8) PAIR_ACC(1,4,12), 6)
    } else if (h == 5) {
        // q16-19: (2,6)(2,7)(3,4)(3,5); mics 2,3,4,5,6,7 -> local 0,1,2,3,4,5
        PAIR_LOOP(LOAD4(0,2) LOAD4(1,3) LOAD4(2,4) LOAD4(3,5) LOAD4(4,6) LOAD4(5,7),
                  PAIR_ACC(0,4,0) PAIR_ACC(0,5,4) PAIR_ACC(1,2,8) PAIR_ACC(1,3,12), 6)
    } else if (h == 6) {
        // q20-23: (3,6)(3,7)(4,5)(4,6); mics 3,4,5,6,7 -> local 0,1,2,3,4
        PAIR_LOOP(LOAD4(0,3) LOAD4(1,4) LOAD4(2,5) LOAD4(3,6) LOAD4(4,7),
                  PAIR_ACC(0,3,0) PAIR_ACC(0,4,4) PAIR_ACC(1,2,8) PAIR_ACC(1,3,12), 5)
    } else {
        // q24-27: (4,7)(5,6)(5,7)(6,7); mics 4,5,6,7 -> local 0,1,2,3
        PAIR_LOOP(LOAD4(0,4) LOAD4(1,5) LOAD4(2,6) LOAD4(3,7),
                  PAIR_ACC(0,3,0) PAIR_ACC(1,2,4) PAIR_ACC(1,3,8) PAIR_ACC(2,3,12), 4)
    }

    // ----- per-wave butterfly reduction, lane 0 -> LDS ------------------------
#pragma unroll
    for (int i = 0; i < 18; ++i) {
        acc[i] += __shfl_xor(acc[i], 1, 64);
        acc[i] += __shfl_xor(acc[i], 2, 64);
        acc[i] += __shfl_xor(acc[i], 4, 64);
        acc[i] += __shfl_xor(acc[i], 8, 64);
        acc[i] += __shfl_xor(acc[i], 16, 64);
        acc[i] += __shfl_xor(acc[i], 32, 64);
    }
    if (l == 0) {
#pragma unroll
        for (int i = 0; i < 18; ++i) sG[h][i] = acc[i];
    }
    __syncthreads();

    // ----- solve: wave 0 only, lane = (r, c) of the 8x8 -----------------------
    if (tid < 64) {
        const int r = tid >> 3, cc = tid & 7;
        const float Ssum = sG[0][0] + 1e-8f;
        const float Nsum = sG[0][1] + 1e-8f;

        float ssr, ssi, ar, ai;
        if (r == cc) {
            ssr = sG[0][2 + r] / Ssum;  ssi = 0.f;
            ar  = sG[0][10 + r] / Nsum + 1e-5f;  ai = 0.f;
        } else {
            const int mm  = (r < cc) ? r : cc;
            const int nn2 = (r < cc) ? cc : r;
            const int q = mm * 8 - mm * (mm + 1) / 2 + nn2 - mm - 1;
            const int g = 1 + (q >> 2);
            const int basei = 4 * (q & 3);
            const float sgn = (r < cc) ? 1.f : -1.f;
            ssr = sG[g][basei] / Ssum;
            ssi = sgn * sG[g][basei + 1] / Ssum;
            ar  = sG[g][basei + 2] / Nsum;
            ai  = sgn * sG[g][basei + 3] / Nsum;
        }

        // Gauss-Jordan inverse of Phi_nn (Hermitian PD)
        float br = (r == cc) ? 1.f : 0.f, bi = 0.f;
        for (int k = 0; k < 8; ++k) {
            const float pr = __shfl(ar, k * 9, 64);
            const float pi = __shfl(ai, k * 9, 64);
            const float den = pr * pr + pi * pi;
            const float qr = pr / den, qi = -pi / den;
            const bool isk = (r == k);
            const float ar2 = ar * qr - ai * qi;
            const float ai2 = ar * qi + ai * qr;
            const float br2 = br * qr - bi * qi;
            const float bi2 = br * qi + bi * qr;
            ar = isk ? ar2 : ar; ai = isk ? ai2 : ai;
            br = isk ? br2 : br; bi = isk ? bi2 : bi;
            const float rar = __shfl(ar, k * 8 + cc, 64);
            const float rai = __shfl(ai, k * 8 + cc, 64);
            const float rbr = __shfl(br, k * 8 + cc, 64);
            const float rbi = __shfl(bi, k * 8 + cc, 64);
            const float fr = __shfl(ar, r * 8 + k, 64);
            const float fi = __shfl(ai, r * 8 + k, 64);
            const float uar = ar - (fr * rar - fi * rai);
            const float uai = ai - (fr * rai + fi * rar);
            const float ubr = br - (fr * rbr - fi * rbi);
            const float ubi = bi - (fr * rbi + fi * rbr);
            ar = isk ? ar : uar; ai = isk ? ai : uai;
            br = isk ? br : ubr; bi = isk ? bi : ubi;
        }

        // G = Phi_nn_inv @ Phi_ss
        float gr = 0.f, gi = 0.f;
        for (int k = 0; k < 8; ++k) {
            const float ir = __shfl(br, r * 8 + k, 64);
            const float ii = __shfl(bi, r * 8 + k, 64);
            const float skr = __shfl(ssr, k * 8 + cc, 64);
            const float ski = __shfl(ssi, k * 8 + cc, 64);
            gr += ir * skr - ii * ski;
            gi += ir * ski + ii * skr;
        }

        // power iteration (30 iters)
        float vr = 1.f, vi = 0.f;
        for (int itp = 0; itp < 30; ++itp) {
            float wr2 = gr * vr - gi * vi;
            float wi2 = gr * vi + gi * vr;
            wr2 += __shfl_xor(wr2, 1, 64); wi2 += __shfl_xor(wi2, 1, 64);
            wr2 += __shfl_xor(wr2, 2, 64); wi2 += __shfl_xor(wi2, 2, 64);
            wr2 += __shfl_xor(wr2, 4, 64); wi2 += __shfl_xor(wi2, 4, 64);
            float nrm = wr2 * wr2 + wi2 * wi2;
            nrm += __shfl_xor(nrm, 8, 64);
            nrm += __shfl_xor(nrm, 16, 64);
            nrm += __shfl_xor(nrm, 32, 64);
            const float inv = 1.f / (sqrtf(nrm) + 1e-12f);
            wr2 *= inv; wi2 *= inv;
            vr = __shfl(wr2, cc * 9, 64);
            vi = __shfl(wi2, cc * 9, 64);
        }

        // rtf = v / (v[0] + 1e-8)
        const float v0r = __shfl(vr, 0, 64) + 1e-8f;
        const float v0i = __shfl(vi, 0, 64);
        const float dd = v0r * v0r + v0i * v0i;
        const float rtr = (vr * v0r + vi * v0i) / dd;
        const float rti = (vi * v0r - vr * v0i) / dd;

        // d = Phi_nn_inv @ rtf
        float dr = br * rtr - bi * rti;
        float di = br * rti + bi * rtr;
        dr += __shfl_xor(dr, 1, 64); di += __shfl_xor(di, 1, 64);
        dr += __shfl_xor(dr, 2, 64); di += __shfl_xor(di, 2, 64);
        dr += __shfl_xor(dr, 4, 64); di += __shfl_xor(di, 4, 64);

        float qden = (r == cc) ? (rtr * dr + rti * di) : 0.f;
        qden += __shfl_xor(qden, 1, 64); qden += __shfl_xor(qden, 2, 64);
        qden += __shfl_xor(qden, 4, 64); qden += __shfl_xor(qden, 8, 64);
        qden += __shfl_xor(qden, 16, 64); qden += __shfl_xor(qden, 32, 64);
        qden += 1e-8f;

        if (cc == 0) {
            const int p = b * F_DIM + f;
            g_w[p * 16 + r]     = dr / qden;
            g_w[p * 16 + 8 + r] = di / qden;
        }
    }
}

// ============================ K2: apply (pure streaming, proven) =============
__launch_bounds__(256, 8)
__global__ void apply_kernel(const float* __restrict__ sre, const float* __restrict__ sim,
                             float* __restrict__ out, int out_mode)
{
    const int f = blockIdx.x, b = blockIdx.y, z = blockIdx.z;
    const int tid = threadIdx.x;
    __shared__ float sW[16];
    const int p = b * F_DIM + f;
    if (tid < 16) sW[tid] = g_w[p * 16 + tid];
    __syncthreads();

    const int t0 = z * 512 + 2 * tid;
    if (t0 >= T_DIM) return;

    const size_t mrow = (size_t)F_DIM * T_DIM;
    const size_t base_bf = ((size_t)(b * M_MICS) * F_DIM + f) * T_DIM;
    const size_t mbase   = ((size_t)b * F_DIM + f) * T_DIM;

    float er0 = 0.f, ei0 = 0.f, er1 = 0.f, ei1 = 0.f;
#pragma unroll
    for (int m = 0; m < 8; ++m) {
        const float2 vr2 = *reinterpret_cast<const float2*>(sre + base_bf + (size_t)m * mrow + t0);
        const float2 vi2 = *reinterpret_cast<const float2*>(sim + base_bf + (size_t)m * mrow + t0);
        const float wr = sW[m], wi = sW[8 + m];
        er0 += wr * vr2.x + wi * vi2.x;
        ei0 += wr * vi2.x - wi * vr2.x;
        er1 += wr * vr2.y + wi * vi2.y;
        ei1 += wr * vi2.y - wi * vr2.y;
    }
    if (out_mode == 2) {
        *reinterpret_cast<float4*>(out + 2 * (mbase + t0)) = make_float4(er0, ei0, er1, ei1);
    } else {
        *reinterpret_cast<float2*>(out + mbase + t0) = make_float2(er0, er1);
    }
}

extern "C" void kernel_launch(void* const* d_in, const int* in_sizes, int n_in,
                              void* d_out, int out_size, void* d_ws, size_t ws_size,
                              hipStream_t stream)
{
    const float* sre   = (const float*)d_in[0];
    const float* sim   = (const float*)d_in[1];
    const float* smask = (const float*)d_in[2];
    const float* nmask = (const float*)d_in[3];
    float* out = (float*)d_out;

    const int mode = (out_size >= 2 * B_DIM * F_DIM * T_DIM) ? 2 : 1;

    cov_solve_kernel<<<dim3(F_DIM, B_DIM), 512, 0, stream>>>(sre, sim, smask, nmask);
    apply_kernel<<<dim3(F_DIM, B_DIM, 4), 256, 0, stream>>>(sre, sim, out, mode);
}